// Round 6
// baseline (197.858 us; speedup 1.0000x reference)
//
#include <hip/hip_runtime.h>
#include <hip/hip_bf16.h>

#define NNODES  50000
#define NPAIRS  25000
#define NSAMP   25
#define FEAT    128
#define TABROWS 100000

typedef __attribute__((ext_vector_type(4))) float  f32x4;
typedef __attribute__((ext_vector_type(8))) __bf16 bf16x8;

__device__ __forceinline__ bf16x8 cvt2(const f32x4 lo, const f32x4 hi) {
  bf16x8 r;
  r[0] = (__bf16)lo[0]; r[1] = (__bf16)lo[1];
  r[2] = (__bf16)lo[2]; r[3] = (__bf16)lo[3];
  r[4] = (__bf16)hi[0]; r[5] = (__bf16)hi[1];
  r[6] = (__bf16)hi[2]; r[7] = (__bf16)hi[3];
  return r;
}

// Pass 1: fp32 table -> bf16 table in workspace (halves gather traffic).
__global__ __launch_bounds__(256)
void cvt_table_kernel(const float* __restrict__ src, __bf16* __restrict__ dst, int n8)
{
  int i = blockIdx.x * blockDim.x + threadIdx.x;
  const int stride = gridDim.x * blockDim.x;
  for (; i < n8; i += stride) {
    f32x4 lo = ((const f32x4*)src)[2 * i];
    f32x4 hi = ((const f32x4*)src)[2 * i + 1];
    ((bf16x8*)dst)[i] = cvt2(lo, hi);
  }
}

// Pass 2: wave-per-NODE-PAIR (2 consecutive nodes per iteration).
//   out[n,f] = (1/25) * sum_s relu(e[nbr[n,s],:] @ W[f,:] + b[f])
// B (=W^T) in LDS in MFMA fragment layout; each (nt,kk) fragment read ONCE
// per pair and fed to 16 MFMAs (4 independent acc chains) -- halves LDS-B
// traffic per node vs 1-node/wave and doubles in-wave MFMA ILP (R5 showed
// 26% MfmaUtil with a 1:2 read:MFMA ratio and 2 chains).
// Bias is folded into the MFMA C-in; pad rows (s>=25) gathered as zero and
// their relu(bias) contribution (7 rows) subtracted inline after the reduce.
// Pair outputs staged through LDS -> one coalesced 1 KB dwordx4 store.
// mfma_f32_16x16x32_bf16; C/D: col=lane&15, row=(lane>>4)*4+reg.
template<int BF16TAB>
__global__ __launch_bounds__(256, 4)
void meanpool_mfma_kernel(const int* __restrict__ nbr,
                          const float* __restrict__ embf32,
                          const __bf16* __restrict__ embbf,
                          const float* __restrict__ W,
                          const float* __restrict__ b,
                          float* __restrict__ out)
{
  __shared__ bf16x8 Blds[8 * 4 * 64];   // 32 KB
  __shared__ float  Ot[4][256];         // 4 KB, per-wave pair-transpose scratch

  const int tid  = threadIdx.x;
  const int lane = tid & 63;
  const int wib  = tid >> 6;
  const int wid  = blockIdx.x * 4 + wib;
  const int nW   = gridDim.x * 4;

  const int col  = lane & 15;   // f within f-tile (B col), s within M-tile (A row)
  const int quad = lane >> 4;   // k-subblock for A/B, row-group for D
  const int coff = quad * 8;    // element offset within a K=32 chunk

  // ---- Fill B LDS: chunk c = nt*256 + kk*64 + l holds
  //      W[nt*16 + (l&15)][kk*32 + (l>>4)*8 .. +7] as bf16x8
  for (int c = tid; c < 2048; c += 256) {
    const int nt = c >> 8;
    const int kk = (c >> 6) & 3;
    const int l  = c & 63;
    const int f  = nt * 16 + (l & 15);
    const int d0 = kk * 32 + (l >> 4) * 8;
    f32x4 lo = *(const f32x4*)(W + f * FEAT + d0);
    f32x4 hi = *(const f32x4*)(W + f * FEAT + d0 + 4);
    Blds[c] = cvt2(lo, hi);
  }

  float bias[8];
  #pragma unroll
  for (int nt = 0; nt < 8; ++nt) bias[nt] = b[nt * 16 + col];

  __syncthreads();

  const float inv = 1.0f / (float)NSAMP;
  const bool  v1 = col < 9;              // tile-1 row (16+col) valid iff col<9
  const bf16x8 zero8 = {};
  float* osc = &Ot[wib][0];

  for (int p = wid; p < NPAIRS; p += nW) {
    const int n0 = 2 * p;
    const int* nbA = nbr + (long long)n0 * NSAMP;
    const int* nbB = nbA + NSAMP;
    const int ia0 = nbA[col];
    const int ia1 = v1 ? nbA[16 + col] : 0;
    const int ib0 = nbB[col];
    const int ib1 = v1 ? nbB[16 + col] : 0;

    // ---- Gather both nodes' A fragments directly in MFMA layout
    bf16x8 Aa0[4], Aa1[4], Ab0[4], Ab1[4];
    if (BF16TAB) {
      const __bf16* ra0 = embbf + (long long)ia0 * FEAT + coff;
      const __bf16* ra1 = embbf + (long long)ia1 * FEAT + coff;
      const __bf16* rb0 = embbf + (long long)ib0 * FEAT + coff;
      const __bf16* rb1 = embbf + (long long)ib1 * FEAT + coff;
      #pragma unroll
      for (int kk = 0; kk < 4; ++kk) {
        Aa0[kk] = *(const bf16x8*)(ra0 + kk * 32);
        Aa1[kk] = v1 ? *(const bf16x8*)(ra1 + kk * 32) : zero8;
        Ab0[kk] = *(const bf16x8*)(rb0 + kk * 32);
        Ab1[kk] = v1 ? *(const bf16x8*)(rb1 + kk * 32) : zero8;
      }
    } else {
      const float* ra0 = embf32 + (long long)ia0 * FEAT + coff;
      const float* ra1 = embf32 + (long long)ia1 * FEAT + coff;
      const float* rb0 = embf32 + (long long)ib0 * FEAT + coff;
      const float* rb1 = embf32 + (long long)ib1 * FEAT + coff;
      const f32x4 z = {0.f, 0.f, 0.f, 0.f};
      #pragma unroll
      for (int kk = 0; kk < 4; ++kk) {
        Aa0[kk] = cvt2(*(const f32x4*)(ra0 + kk * 32), *(const f32x4*)(ra0 + kk * 32 + 4));
        Aa1[kk] = v1 ? cvt2(*(const f32x4*)(ra1 + kk * 32), *(const f32x4*)(ra1 + kk * 32 + 4)) : cvt2(z, z);
        Ab0[kk] = cvt2(*(const f32x4*)(rb0 + kk * 32), *(const f32x4*)(rb0 + kk * 32 + 4));
        Ab1[kk] = v1 ? cvt2(*(const f32x4*)(rb1 + kk * 32), *(const f32x4*)(rb1 + kk * 32 + 4)) : cvt2(z, z);
      }
    }

    #pragma unroll
    for (int nt = 0; nt < 8; ++nt) {
      const float bn = bias[nt];
      f32x4 acc0a = {bn, bn, bn, bn};   // bias folded into C-in
      f32x4 acc1a = {bn, bn, bn, bn};
      f32x4 acc0b = {bn, bn, bn, bn};
      f32x4 acc1b = {bn, bn, bn, bn};
      #pragma unroll
      for (int kk = 0; kk < 4; ++kk) {
        const bf16x8 Bf = Blds[nt * 256 + kk * 64 + lane];
        acc0a = __builtin_amdgcn_mfma_f32_16x16x32_bf16(Aa0[kk], Bf, acc0a, 0, 0, 0);
        acc1a = __builtin_amdgcn_mfma_f32_16x16x32_bf16(Aa1[kk], Bf, acc1a, 0, 0, 0);
        acc0b = __builtin_amdgcn_mfma_f32_16x16x32_bf16(Ab0[kk], Bf, acc0b, 0, 0, 0);
        acc1b = __builtin_amdgcn_mfma_f32_16x16x32_bf16(Ab1[kk], Bf, acc1b, 0, 0, 0);
      }
      // relu + per-lane partial mean-pool (pad rows contribute relu(bias))
      float psA = 0.f, psB = 0.f;
      #pragma unroll
      for (int j = 0; j < 4; ++j) {
        psA += fmaxf(acc0a[j], 0.f) + fmaxf(acc1a[j], 0.f);
        psB += fmaxf(acc0b[j], 0.f) + fmaxf(acc1b[j], 0.f);
      }
      psA += __shfl_xor(psA, 16);  psA += __shfl_xor(psA, 32);
      psB += __shfl_xor(psB, 16);  psB += __shfl_xor(psB, 32);
      const float corr = 7.0f * fmaxf(bias[nt], 0.f);   // 7 pad rows
      if (quad == 0) osc[nt * 16 + col]       = (psA - corr) * inv;
      if (quad == 1) osc[128 + nt * 16 + col] = (psB - corr) * inv;
    }
    // DS ops in-order within a wave; drain writes before the transpose read
    asm volatile("s_waitcnt lgkmcnt(0)" ::: "memory");
    const f32x4 o4 = *(const f32x4*)(osc + 4 * lane);
    *(f32x4*)(out + (long long)n0 * FEAT + 4 * lane) = o4;  // 1 KB coalesced/pair
  }
}

extern "C" void kernel_launch(void* const* d_in, const int* in_sizes, int n_in,
                              void* d_out, int out_size, void* d_ws, size_t ws_size,
                              hipStream_t stream) {
  const int*   nbr = (const int*)d_in[0];
  const float* emb = (const float*)d_in[1];
  const float* W   = (const float*)d_in[2];
  const float* b   = (const float*)d_in[3];
  float* out = (float*)d_out;

  const size_t tabBytes = (size_t)TABROWS * FEAT * sizeof(__bf16);
  const bool useBf16 = ws_size >= tabBytes;

  if (useBf16) {
    __bf16* tab = (__bf16*)d_ws;
    const int n8 = TABROWS * FEAT / 8;
    hipLaunchKernelGGL(cvt_table_kernel, dim3(2048), dim3(256), 0, stream,
                       emb, tab, n8);
    hipLaunchKernelGGL((meanpool_mfma_kernel<1>), dim3(2048), dim3(256), 0, stream,
                       nbr, emb, tab, W, b, out);
  } else {
    hipLaunchKernelGGL((meanpool_mfma_kernel<0>), dim3(2048), dim3(256), 0, stream,
                       nbr, emb, (const __bf16*)nullptr, W, b, out);
  }
}